// Round 15
// baseline (158.689 us; speedup 1.0000x reference)
//
#include <hip/hip_runtime.h>
#include <cstdint>
#include <cstddef>

#define BATCH 256
#define NN 400
#define HH 256
#define TDIM 128
#define HALFD 64
#define OUTD 800
#define BITW 16     // u32 words per bitmap row in global (13 written/used)
#define BMW 13
#define Y2S 424     // y2 LDS row stride (shorts): dword-stride 212 -> 2-way banks (free)

using short8  = __attribute__((ext_vector_type(8))) short;
using short4v = __attribute__((ext_vector_type(4))) short;
using f32x4   = __attribute__((ext_vector_type(4))) float;

__device__ __forceinline__ short f2bf_trunc(float x) {
  union { float f; unsigned int u; } c; c.f = x; return (short)(c.u >> 16);
}
__device__ __forceinline__ short f2bf_rne(float x) {
  union { float f; unsigned int u; } c; c.f = x;
  unsigned int r = c.u + 0x7FFFu + ((c.u >> 16) & 1u);
  return (short)(r >> 16);
}

// ---- K1: adj -> bitmap [256][400][16 u32] (binary + self loop).
//      Trimmed: no dis/dd outputs, no count reduction; writes words 0..12 only.
__global__ __launch_bounds__(256) void k_prep(const float* __restrict__ adj,
    unsigned int* __restrict__ bits) {
  int bg = blockIdx.x;
  int rbase = blockIdx.y * 16;
  int wv = threadIdx.x >> 6, lane = threadIdx.x & 63;
#pragma unroll
  for (int rr = 0; rr < 4; ++rr) {
    int i = rbase + wv * 4 + rr;
    const float* arow = adj + ((size_t)bg * NN + i) * NN;
    unsigned int b8 = 0;
    if (lane < 50) {
      float4 v0 = *(const float4*)(arow + 8 * lane);
      float4 v1 = *(const float4*)(arow + 8 * lane + 4);
      b8 = (v0.x != 0.f ? 1u : 0u) | (v0.y != 0.f ? 2u : 0u) |
           (v0.z != 0.f ? 4u : 0u) | (v0.w != 0.f ? 8u : 0u) |
           (v1.x != 0.f ? 16u : 0u) | (v1.y != 0.f ? 32u : 0u) |
           (v1.z != 0.f ? 64u : 0u) | (v1.w != 0.f ? 128u : 0u);
      if ((i >> 3) == lane) b8 |= 1u << (i & 7);  // self loop
    }
    unsigned int p0 = (unsigned int)__shfl((int)b8, 4 * lane);
    unsigned int p1 = (unsigned int)__shfl((int)b8, 4 * lane + 1);
    unsigned int p2 = (unsigned int)__shfl((int)b8, 4 * lane + 2);
    unsigned int p3 = (unsigned int)__shfl((int)b8, 4 * lane + 3);
    if (lane < BMW)
      bits[((size_t)bg * NN + i) * BITW + lane] =
          p0 | (p1 << 8) | (p2 << 16) | (p3 << 24);
  }
}

// ---- K2: merged tproj + W2-swizzle.
//      blocks 0..255: tproj[b,h] = temb(times[b]) @ W1[1:,:]
//      blocks 256..287: W2s[((q*8+k0)*4+f)*512 + lane*8+e] = bf16 W2 fragment
__global__ __launch_bounds__(256) void k_tw(
    const float* __restrict__ times, const float* __restrict__ W1,
    float* __restrict__ tproj, const float* __restrict__ W2,
    short* __restrict__ W2s) {
  __shared__ float te[TDIM];
  int t = threadIdx.x;
  if (blockIdx.x < 256) {
    int b = blockIdx.x;
    if (t < HALFD) {
      float f = expf(-9.210340371976184f * (float)t / (float)(HALFD - 1));
      float arg = times[b] * f;
      te[t] = sinf(arg);
      te[t + HALFD] = cosf(arg);
    }
    __syncthreads();
    float acc = 0.f;
#pragma unroll 8
    for (int k = 0; k < TDIM; ++k) acc += te[k] * W1[(1 + k) * HH + t];
    tproj[b * HH + t] = acc;
  } else {
    int blk = (blockIdx.x - 256) * 4 + (t >> 6);  // 0..127 = (q*8+k0)*4+f
    int lane = t & 63;
    int q = blk >> 5, k0 = (blk >> 2) & 7, f = blk & 3;
    int n = q * 64 + f * 16 + (lane & 15);
    int kb = k0 * 32 + (lane >> 4) * 8;
    short8 v;
#pragma unroll
    for (int e = 0; e < 8; ++e) v[e] = f2bf_rne(W2[(size_t)(kb + e) * HH + n]);
    *(short8*)(W2s + (size_t)blk * 512 + lane * 8) = v;
  }
}

// ---- K3: fused per-(graph, n-quarter). R14 body + folded pq prologue
//      (sd/su from bmpL popcount, ctz-walk in LDS). GEMM1/AGG/epilogue identical.
__global__ __launch_bounds__(512, 2) void k_fused(
    const unsigned int* __restrict__ bits, const short* __restrict__ W2s,
    const float* __restrict__ W1, const float* __restrict__ b1,
    const float* __restrict__ tproj, const float* __restrict__ b2,
    float* __restrict__ pooled) {
  extern __shared__ char smem[];
  short* y2q         = (short*)smem;                  // 64*424*2 = 54272
  unsigned int* bmpL = (unsigned int*)(smem + 54272); // 400*13*4 = 20800 -> 75072
  float* sd          = (float*)(smem + 75072);        // 1600 -> 76672
  float* su          = (float*)(smem + 76672);        // 1600 -> 78272
  float* ppL         = (float*)(smem + 78272);        // 1600 -> 79872
  float* qqL         = (float*)(smem + 79872);        // 1600 -> 81472
  short* lut4        = (short*)(smem + 81472);        // 128 -> 81600 total
  float* pool        = (float*)(smem + 76672);        // alias su+ppL (dead after GEMM1)

  int t = threadIdx.x;
  int wv = t >> 6, lane = t & 63, l15 = lane & 15, l4 = lane >> 4;
  int bg = blockIdx.x, q = blockIdx.y;

  // ---- stage: bitmap -> bmpL; sd/su from popcount (pc = deg+1 incl self bit)
  if (t < NN) {
    const uint4* bp = (const uint4*)(bits + ((size_t)bg * NN + t) * BITW);
    uint4 qa = bp[0], qb = bp[1], qc = bp[2];
    unsigned int w12 = ((const unsigned int*)bp)[12];
    bmpL[t * BMW + 0] = qa.x;  bmpL[t * BMW + 1] = qa.y;
    bmpL[t * BMW + 2] = qa.z;  bmpL[t * BMW + 3] = qa.w;
    bmpL[t * BMW + 4] = qb.x;  bmpL[t * BMW + 5] = qb.y;
    bmpL[t * BMW + 6] = qb.z;  bmpL[t * BMW + 7] = qb.w;
    bmpL[t * BMW + 8] = qc.x;  bmpL[t * BMW + 9] = qc.y;
    bmpL[t * BMW + 10] = qc.z; bmpL[t * BMW + 11] = qc.w;
    bmpL[t * BMW + 12] = w12;
    int pc = __popc(qa.x) + __popc(qa.y) + __popc(qa.z) + __popc(qa.w) +
             __popc(qb.x) + __popc(qb.y) + __popc(qb.z) + __popc(qb.w) +
             __popc(qc.x) + __popc(qc.y) + __popc(qc.z) + __popc(qc.w) +
             __popc(w12);
    float d = rsqrtf((float)pc);        // pc = deg + 1
    sd[t] = d;
    su[t] = d * (float)(pc - 1);
  }
  if (t < 192) {  // zero y2q pad cols m=400..423 for all 64 n-rows
    int n = t / 3, c = t % 3;
    short8 z = {};
    *(short8*)(y2q + n * Y2S + 400 + c * 8) = z;
  }
  if (t < 16) {   // nibble LUT: lut4[n][e] = bit e of n as bf16 1.0/0.0
    short4v v;
#pragma unroll
    for (int e = 0; e < 4; ++e) v[e] = ((t >> e) & 1) ? (short)0x3F80 : (short)0;
    *(short4v*)(lut4 + t * 4) = v;
  }
  __syncthreads();

  // ---- folded pq: pp = dis_i*(As@su), qq = dis_i*(As@sd) via ctz-walk on bmpL
  if (t < NN) {
    float ps = 0.f, qs = 0.f;
#pragma unroll
    for (int wi = 0; wi < BMW; ++wi) {
      unsigned int u = bmpL[t * BMW + wi];
      int base = wi * 32;
      while (u) {
        int j = base + __builtin_ctz(u);
        u &= u - 1;
        ps += su[j]; qs += sd[j];
      }
    }
    float d = sd[t];
    ppL[t] = d * ps;
    qqL[t] = d * qs;
  }
  __syncthreads();

  // ---- GEMM1: y2q[n][m] = dis_m * (g1 @ W2)[m][q*64+n]; k0 outer, mt inner
  const float* tpr = tproj + bg * HH;
  const short* w2b = W2s + (size_t)q * 8 * 4 * 512;
  float pv[4], qv[4];
#pragma unroll
  for (int mi = 0; mi < 4; ++mi) {
    int mt = wv + mi * 8;
    int arow = mt * 16 + l15;
    pv[mi] = (mt < 25) ? ppL[arow] : 0.f;
    qv[mi] = (mt < 25) ? qqL[arow] : 0.f;
  }
  f32x4 acc[4][4];
#pragma unroll
  for (int mi = 0; mi < 4; ++mi)
#pragma unroll
    for (int f = 0; f < 4; ++f) acc[mi][f] = (f32x4){0.f, 0.f, 0.f, 0.f};

#pragma unroll
  for (int k0 = 0; k0 < 8; ++k0) {
    int kk = k0 * 32 + l4 * 8;
    float4 w1a = *(const float4*)(W1 + kk), w1b = *(const float4*)(W1 + kk + 4);
    float4 b1a = *(const float4*)(b1 + kk), b1b = *(const float4*)(b1 + kk + 4);
    float4 tpa = *(const float4*)(tpr + kk), tpb = *(const float4*)(tpr + kk + 4);
    short8 bf[4];
#pragma unroll
    for (int f = 0; f < 4; ++f)
      bf[f] = *(const short8*)(w2b + (size_t)(k0 * 4 + f) * 512 + lane * 8);
#pragma unroll
    for (int mi = 0; mi < 4; ++mi) {
      if (wv + mi * 8 < 25) {
        float ppv = pv[mi], qqv = qv[mi];
        short8 af;
        af[0] = f2bf_trunc(fmaxf(ppv * w1a.x + qqv * tpa.x + b1a.x, 0.f));
        af[1] = f2bf_trunc(fmaxf(ppv * w1a.y + qqv * tpa.y + b1a.y, 0.f));
        af[2] = f2bf_trunc(fmaxf(ppv * w1a.z + qqv * tpa.z + b1a.z, 0.f));
        af[3] = f2bf_trunc(fmaxf(ppv * w1a.w + qqv * tpa.w + b1a.w, 0.f));
        af[4] = f2bf_trunc(fmaxf(ppv * w1b.x + qqv * tpb.x + b1b.x, 0.f));
        af[5] = f2bf_trunc(fmaxf(ppv * w1b.y + qqv * tpb.y + b1b.y, 0.f));
        af[6] = f2bf_trunc(fmaxf(ppv * w1b.z + qqv * tpb.z + b1b.z, 0.f));
        af[7] = f2bf_trunc(fmaxf(ppv * w1b.w + qqv * tpb.w + b1b.w, 0.f));
#pragma unroll
        for (int f = 0; f < 4; ++f)
          acc[mi][f] = __builtin_amdgcn_mfma_f32_16x16x32_bf16(af, bf[f], acc[mi][f], 0, 0, 0);
      }
    }
  }
  // write y2q (transposed, dis-scaled): n = f*16+l15, m = mt*16 + l4*4 + r
#pragma unroll
  for (int mi = 0; mi < 4; ++mi) {
    int mt = wv + mi * 8;
    if (mt < 25) {
      float4 d4 = *(const float4*)(sd + mt * 16 + l4 * 4);
#pragma unroll
      for (int f = 0; f < 4; ++f) {
        short4v pk;
        pk[0] = f2bf_trunc(d4.x * acc[mi][f][0]);
        pk[1] = f2bf_trunc(d4.y * acc[mi][f][1]);
        pk[2] = f2bf_trunc(d4.z * acc[mi][f][2]);
        pk[3] = f2bf_trunc(d4.w * acc[mi][f][3]);
        *(short4v*)(y2q + (f * 16 + l15) * Y2S + mt * 16 + l4 * 4) = pk;
      }
    }
  }
  __syncthreads();

  // ---- AGG: C[m][n] = sum_k As[m][k]*y2q[n][k]; A-frags via nibble LUT
  f32x4 acc2[4][4];
#pragma unroll
  for (int mi = 0; mi < 4; ++mi)
#pragma unroll
    for (int f = 0; f < 4; ++f) acc2[mi][f] = (f32x4){0.f, 0.f, 0.f, 0.f};

#pragma unroll
  for (int ks = 0; ks < 13; ++ks) {
    short8 bfv[4];
#pragma unroll
    for (int f = 0; f < 4; ++f)
      bfv[f] = *(const short8*)(y2q + (f * 16 + l15) * Y2S + ks * 32 + l4 * 8);
#pragma unroll
    for (int mi = 0; mi < 4; ++mi) {
      int mt = wv + mi * 8;
      if (mt < 25) {
        unsigned int wd = bmpL[(mt * 16 + l15) * BMW + ks];
        unsigned int byt = (wd >> (l4 * 8)) & 0xFFu;
        short4v lo = *(const short4v*)(lut4 + (byt & 15u) * 4);
        short4v hi = *(const short4v*)(lut4 + (byt >> 4) * 4);
        short8 af;
        af[0] = lo[0]; af[1] = lo[1]; af[2] = lo[2]; af[3] = lo[3];
        af[4] = hi[0]; af[5] = hi[1]; af[6] = hi[2]; af[7] = hi[3];
#pragma unroll
        for (int f = 0; f < 4; ++f)
          acc2[mi][f] = __builtin_amdgcn_mfma_f32_16x16x32_bf16(af, bfv[f], acc2[mi][f], 0, 0, 0);
      }
    }
  }

  // ---- epilogue: s(n) = sum_m relu(dis_m * C[m][n] + b2[n]); pool across waves
#pragma unroll
  for (int f = 0; f < 4; ++f) {
    float b2v = b2[q * 64 + f * 16 + l15];
    float s = 0.f;
#pragma unroll
    for (int mi = 0; mi < 4; ++mi) {
      int mt = wv + mi * 8;
      if (mt < 25) {
        float4 d4 = *(const float4*)(sd + mt * 16 + l4 * 4);
        s += fmaxf(d4.x * acc2[mi][f][0] + b2v, 0.f)
           + fmaxf(d4.y * acc2[mi][f][1] + b2v, 0.f)
           + fmaxf(d4.z * acc2[mi][f][2] + b2v, 0.f)
           + fmaxf(d4.w * acc2[mi][f][3] + b2v, 0.f);
      }
    }
    s += __shfl_xor(s, 16);
    s += __shfl_xor(s, 32);
    if (l4 == 0) pool[wv * 64 + f * 16 + l15] = s;  // pool aliases dead su/ppL
  }
  __syncthreads();
  if (t < 64) {
    float sum = 0.f;
#pragma unroll
    for (int w8 = 0; w8 < 8; ++w8) sum += pool[w8 * 64 + t];
    pooled[(size_t)bg * HH + q * 64 + t] = sum;
  }
}

// ---- K4: logits = (pooled/400) @ Wlin + blin. 2 graphs per block. (unchanged)
__global__ __launch_bounds__(256) void k_out(
    const float* __restrict__ pooled, const float* __restrict__ Wlin,
    const float* __restrict__ blin, float* __restrict__ out) {
  int bb = blockIdx.x * 2, t = threadIdx.x;
  __shared__ float ps[2][HH];
  ps[0][t] = pooled[(size_t)bb * HH + t] * (1.f / 400.f);
  ps[1][t] = pooled[(size_t)(bb + 1) * HH + t] * (1.f / 400.f);
  __syncthreads();
#pragma unroll
  for (int c = 0; c < 4; ++c) {
    int o = t + c * 256;
    if (o < OUTD) {
      float a0 = blin[o], a1 = a0;
#pragma unroll 8
      for (int h = 0; h < HH; ++h) {
        float wv = Wlin[h * OUTD + o];
        a0 += ps[0][h] * wv;
        a1 += ps[1][h] * wv;
      }
      out[(size_t)bb * OUTD + o] = a0;
      out[(size_t)(bb + 1) * OUTD + o] = a1;
    }
  }
}

extern "C" void kernel_launch(void* const* d_in, const int* in_sizes, int n_in,
                              void* d_out, int out_size, void* d_ws, size_t ws_size,
                              hipStream_t stream) {
  const float* adj   = (const float*)d_in[0];
  const float* times = (const float*)d_in[1];
  const float* W1    = (const float*)d_in[2];
  const float* b1    = (const float*)d_in[3];
  const float* W2    = (const float*)d_in[4];
  const float* b2    = (const float*)d_in[5];
  const float* Wlin  = (const float*)d_in[6];
  const float* blin  = (const float*)d_in[7];
  float* out = (float*)d_out;

  char* ws = (char*)d_ws;
  size_t off = 0;
  auto alloc = [&](size_t bytes) -> void* {
    void* ptr = ws + off;
    off = (off + bytes + 255) & ~(size_t)255;
    return ptr;
  };
  float* tproj  = (float*)alloc((size_t)BATCH * HH * 4);
  float* pooled = (float*)alloc((size_t)BATCH * HH * 4);
  short* W2s    = (short*)alloc((size_t)128 * 512 * 2);
  unsigned int* bits = (unsigned int*)alloc((size_t)BATCH * NN * BITW * 4);

  k_tw<<<288, 256, 0, stream>>>(times, W1, tproj, W2, W2s);
  k_prep<<<dim3(BATCH, 25), 256, 0, stream>>>(adj, bits);
  k_fused<<<dim3(BATCH, 4), 512, 81600, stream>>>(
      bits, W2s, W1, b1, tproj, b2, pooled);
  k_out<<<128, 256, 0, stream>>>(pooled, Wlin, blin, out);
}

// Round 16
// 149.836 us; speedup vs baseline: 1.0591x; 1.0591x over previous
//
#include <hip/hip_runtime.h>
#include <cstdint>
#include <cstddef>

#define BATCH 256
#define NN 400
#define HH 256
#define TDIM 128
#define HALFD 64
#define OUTD 800
#define BITW 16     // u32 words per bitmap row in global (13 used)
#define BMW 13
#define Y2S 424     // y2 LDS row stride (shorts): dword-stride 212 -> 2-way banks (free)

using short8  = __attribute__((ext_vector_type(8))) short;
using short4v = __attribute__((ext_vector_type(4))) short;
using f32x4   = __attribute__((ext_vector_type(4))) float;

__device__ __forceinline__ short f2bf_trunc(float x) {
  union { float f; unsigned int u; } c; c.f = x; return (short)(c.u >> 16);
}
__device__ __forceinline__ short f2bf_rne(float x) {
  union { float f; unsigned int u; } c; c.f = x;
  unsigned int r = c.u + 0x7FFFu + ((c.u >> 16) & 1u);
  return (short)(r >> 16);
}

// ---- K1: adj -> bitmap [256][400][16 u32] (binary + self loop), dis, dd.
//      (byte-identical to R14's passing version)
__global__ __launch_bounds__(256) void k_prep(const float* __restrict__ adj,
    unsigned int* __restrict__ bits, float* __restrict__ dis,
    float* __restrict__ dd) {
  int bg = blockIdx.x;
  int rbase = blockIdx.y * 16;
  int wv = threadIdx.x >> 6, lane = threadIdx.x & 63;
#pragma unroll
  for (int rr = 0; rr < 4; ++rr) {
    int i = rbase + wv * 4 + rr;
    const float* arow = adj + ((size_t)bg * NN + i) * NN;
    unsigned int b8 = 0; int c = 0;
    if (lane < 50) {
      float4 v0 = *(const float4*)(arow + 8 * lane);
      float4 v1 = *(const float4*)(arow + 8 * lane + 4);
      b8 = (v0.x != 0.f ? 1u : 0u) | (v0.y != 0.f ? 2u : 0u) |
           (v0.z != 0.f ? 4u : 0u) | (v0.w != 0.f ? 8u : 0u) |
           (v1.x != 0.f ? 16u : 0u) | (v1.y != 0.f ? 32u : 0u) |
           (v1.z != 0.f ? 64u : 0u) | (v1.w != 0.f ? 128u : 0u);
      c = __popc(b8);
      if ((i >> 3) == lane) b8 |= 1u << (i & 7);  // self loop
    }
    int cs = c;
#pragma unroll
    for (int s = 32; s; s >>= 1) cs += __shfl_xor(cs, s);
    unsigned int p0 = (unsigned int)__shfl((int)b8, 4 * lane);
    unsigned int p1 = (unsigned int)__shfl((int)b8, 4 * lane + 1);
    unsigned int p2 = (unsigned int)__shfl((int)b8, 4 * lane + 2);
    unsigned int p3 = (unsigned int)__shfl((int)b8, 4 * lane + 3);
    if (lane < BITW)
      bits[((size_t)bg * NN + i) * BITW + lane] =
          (lane < BMW) ? (p0 | (p1 << 8) | (p2 << 16) | (p3 << 24)) : 0u;
    if (lane == 0) {
      float d = rsqrtf((float)cs + 1.f);
      dis[bg * NN + i] = d;
      dd[bg * NN + i] = d * (float)cs;
    }
  }
}

// ---- K2: merged tproj + W2-swizzle (proven in R15).
//      blocks 0..255: tproj[b,h] = temb(times[b]) @ W1[1:,:]
//      blocks 256..287: W2s[((q*8+k0)*4+f)*512 + lane*8+e] = bf16 W2 fragment
__global__ __launch_bounds__(256) void k_tw(
    const float* __restrict__ times, const float* __restrict__ W1,
    float* __restrict__ tproj, const float* __restrict__ W2,
    short* __restrict__ W2s) {
  __shared__ float te[TDIM];
  int t = threadIdx.x;
  if (blockIdx.x < 256) {
    int b = blockIdx.x;
    if (t < HALFD) {
      float f = expf(-9.210340371976184f * (float)t / (float)(HALFD - 1));
      float arg = times[b] * f;
      te[t] = sinf(arg);
      te[t + HALFD] = cosf(arg);
    }
    __syncthreads();
    float acc = 0.f;
#pragma unroll 8
    for (int k = 0; k < TDIM; ++k) acc += te[k] * W1[(1 + k) * HH + t];
    tproj[b * HH + t] = acc;
  } else {
    int blk = (blockIdx.x - 256) * 4 + (t >> 6);  // 0..127 = (q*8+k0)*4+f
    int lane = t & 63;
    int q = blk >> 5, k0 = (blk >> 2) & 7, f = blk & 3;
    int n = q * 64 + f * 16 + (lane & 15);
    int kb = k0 * 32 + (lane >> 4) * 8;
    short8 v;
#pragma unroll
    for (int e = 0; e < 8; ++e) v[e] = f2bf_rne(W2[(size_t)(kb + e) * HH + n]);
    *(short8*)(W2s + (size_t)blk * 512 + lane * 8) = v;
  }
}

// ---- K3: pp/qq via bitmap ctz-walk (byte-identical to R14)
__global__ __launch_bounds__(512) void k_pq(const unsigned int* __restrict__ bits,
    const float* __restrict__ dis, const float* __restrict__ dd,
    float* __restrict__ pp, float* __restrict__ qq) {
  int bg = blockIdx.x, t = threadIdx.x;
  __shared__ float sd[NN], su[NN];
  for (int j = t; j < NN; j += 512) { sd[j] = dis[bg * NN + j]; su[j] = dd[bg * NN + j]; }
  __syncthreads();
  if (t >= NN) return;
  const uint4* bp = (const uint4*)(bits + ((size_t)bg * NN + t) * BITW);
  uint4 qa = bp[0], qb = bp[1], qc = bp[2];
  unsigned int wr[13] = {qa.x, qa.y, qa.z, qa.w, qb.x, qb.y, qb.z, qb.w,
                         qc.x, qc.y, qc.z, qc.w, ((const unsigned int*)bp)[12]};
  float ps = 0.f, qs = 0.f;
#pragma unroll
  for (int w = 0; w < BMW; ++w) {
    unsigned int u = wr[w];
    int base = w * 32;
    while (u) {
      int j = base + __builtin_ctz(u);
      u &= u - 1;
      ps += su[j]; qs += sd[j];
    }
  }
  float d = sd[t];
  pp[bg * NN + t] = d * ps;
  qq[bg * NN + t] = d * qs;
}

// ---- K4: fused per-(graph, n-quarter). Byte-identical to R14's passing k_fused.
__global__ __launch_bounds__(512, 2) void k_fused(
    const unsigned int* __restrict__ bits, const float* __restrict__ disg,
    const float* __restrict__ ppg, const float* __restrict__ qqg,
    const short* __restrict__ W2s, const float* __restrict__ W1,
    const float* __restrict__ b1, const float* __restrict__ tproj,
    const float* __restrict__ b2, float* __restrict__ pooled) {
  extern __shared__ char smem[];
  short* y2q         = (short*)smem;                  // 64*424*2 = 54272
  unsigned int* bmpL = (unsigned int*)(smem + 54272); // 400*13*4 = 20800 -> 75072
  float* sd          = (float*)(smem + 75072);        // 1600 -> 76672
  float* ppL         = (float*)(smem + 76672);        // 1600 -> 78272
  float* qqL         = (float*)(smem + 78272);        // 1600 -> 79872
  short* lut4        = (short*)(smem + 79872);        // 16*4*2 = 128 -> 80000 total
  float* pool        = (float*)(smem + 76672);        // alias ppL+qqL (dead after GEMM1)

  int t = threadIdx.x;
  int wv = t >> 6, lane = t & 63, l15 = lane & 15, l4 = lane >> 4;
  int bg = blockIdx.x, q = blockIdx.y;

  // ---- stage: bitmap, dis/pp/qq, LUT, zero y2q pad (m=400..423)
  if (t < NN) {
    const uint4* bp = (const uint4*)(bits + ((size_t)bg * NN + t) * BITW);
    uint4 qa = bp[0], qb = bp[1], qc = bp[2];
    bmpL[t * BMW + 0] = qa.x;  bmpL[t * BMW + 1] = qa.y;
    bmpL[t * BMW + 2] = qa.z;  bmpL[t * BMW + 3] = qa.w;
    bmpL[t * BMW + 4] = qb.x;  bmpL[t * BMW + 5] = qb.y;
    bmpL[t * BMW + 6] = qb.z;  bmpL[t * BMW + 7] = qb.w;
    bmpL[t * BMW + 8] = qc.x;  bmpL[t * BMW + 9] = qc.y;
    bmpL[t * BMW + 10] = qc.z; bmpL[t * BMW + 11] = qc.w;
    bmpL[t * BMW + 12] = ((const unsigned int*)bp)[12];
    sd[t] = disg[bg * NN + t];
    ppL[t] = ppg[bg * NN + t];
    qqL[t] = qqg[bg * NN + t];
  }
  if (t < 192) {  // zero y2q pad cols m=400..423 for all 64 n-rows
    int n = t / 3, c = t % 3;
    short8 z = {};
    *(short8*)(y2q + n * Y2S + 400 + c * 8) = z;
  }
  if (t < 16) {   // nibble LUT: lut4[n][e] = bit e of n as bf16 1.0/0.0
    short4v v;
#pragma unroll
    for (int e = 0; e < 4; ++e) v[e] = ((t >> e) & 1) ? (short)0x3F80 : (short)0;
    *(short4v*)(lut4 + t * 4) = v;
  }
  __syncthreads();

  // ---- GEMM1: y2q[n][m] = dis_m * (g1 @ W2)[m][q*64+n]; k0 outer, mt inner
  const float* tpr = tproj + bg * HH;
  const short* w2b = W2s + (size_t)q * 8 * 4 * 512;
  float pv[4], qv[4];
#pragma unroll
  for (int mi = 0; mi < 4; ++mi) {
    int mt = wv + mi * 8;
    int arow = mt * 16 + l15;
    pv[mi] = (mt < 25) ? ppL[arow] : 0.f;
    qv[mi] = (mt < 25) ? qqL[arow] : 0.f;
  }
  f32x4 acc[4][4];
#pragma unroll
  for (int mi = 0; mi < 4; ++mi)
#pragma unroll
    for (int f = 0; f < 4; ++f) acc[mi][f] = (f32x4){0.f, 0.f, 0.f, 0.f};

#pragma unroll
  for (int k0 = 0; k0 < 8; ++k0) {
    int kk = k0 * 32 + l4 * 8;
    float4 w1a = *(const float4*)(W1 + kk), w1b = *(const float4*)(W1 + kk + 4);
    float4 b1a = *(const float4*)(b1 + kk), b1b = *(const float4*)(b1 + kk + 4);
    float4 tpa = *(const float4*)(tpr + kk), tpb = *(const float4*)(tpr + kk + 4);
    short8 bf[4];
#pragma unroll
    for (int f = 0; f < 4; ++f)
      bf[f] = *(const short8*)(w2b + (size_t)(k0 * 4 + f) * 512 + lane * 8);
#pragma unroll
    for (int mi = 0; mi < 4; ++mi) {
      if (wv + mi * 8 < 25) {
        float ppv = pv[mi], qqv = qv[mi];
        short8 af;
        af[0] = f2bf_trunc(fmaxf(ppv * w1a.x + qqv * tpa.x + b1a.x, 0.f));
        af[1] = f2bf_trunc(fmaxf(ppv * w1a.y + qqv * tpa.y + b1a.y, 0.f));
        af[2] = f2bf_trunc(fmaxf(ppv * w1a.z + qqv * tpa.z + b1a.z, 0.f));
        af[3] = f2bf_trunc(fmaxf(ppv * w1a.w + qqv * tpa.w + b1a.w, 0.f));
        af[4] = f2bf_trunc(fmaxf(ppv * w1b.x + qqv * tpb.x + b1b.x, 0.f));
        af[5] = f2bf_trunc(fmaxf(ppv * w1b.y + qqv * tpb.y + b1b.y, 0.f));
        af[6] = f2bf_trunc(fmaxf(ppv * w1b.z + qqv * tpb.z + b1b.z, 0.f));
        af[7] = f2bf_trunc(fmaxf(ppv * w1b.w + qqv * tpb.w + b1b.w, 0.f));
#pragma unroll
        for (int f = 0; f < 4; ++f)
          acc[mi][f] = __builtin_amdgcn_mfma_f32_16x16x32_bf16(af, bf[f], acc[mi][f], 0, 0, 0);
      }
    }
  }
  // write y2q (transposed, dis-scaled): n = f*16+l15, m = mt*16 + l4*4 + r
#pragma unroll
  for (int mi = 0; mi < 4; ++mi) {
    int mt = wv + mi * 8;
    if (mt < 25) {
      float4 d4 = *(const float4*)(sd + mt * 16 + l4 * 4);
#pragma unroll
      for (int f = 0; f < 4; ++f) {
        short4v pk;
        pk[0] = f2bf_trunc(d4.x * acc[mi][f][0]);
        pk[1] = f2bf_trunc(d4.y * acc[mi][f][1]);
        pk[2] = f2bf_trunc(d4.z * acc[mi][f][2]);
        pk[3] = f2bf_trunc(d4.w * acc[mi][f][3]);
        *(short4v*)(y2q + (f * 16 + l15) * Y2S + mt * 16 + l4 * 4) = pk;
      }
    }
  }
  __syncthreads();

  // ---- AGG: C[m][n] = sum_k As[m][k]*y2q[n][k]; A-frags via nibble LUT
  f32x4 acc2[4][4];
#pragma unroll
  for (int mi = 0; mi < 4; ++mi)
#pragma unroll
    for (int f = 0; f < 4; ++f) acc2[mi][f] = (f32x4){0.f, 0.f, 0.f, 0.f};

#pragma unroll
  for (int ks = 0; ks < 13; ++ks) {
    short8 bfv[4];
#pragma unroll
    for (int f = 0; f < 4; ++f)
      bfv[f] = *(const short8*)(y2q + (f * 16 + l15) * Y2S + ks * 32 + l4 * 8);
#pragma unroll
    for (int mi = 0; mi < 4; ++mi) {
      int mt = wv + mi * 8;
      if (mt < 25) {
        unsigned int wd = bmpL[(mt * 16 + l15) * BMW + ks];
        unsigned int byt = (wd >> (l4 * 8)) & 0xFFu;
        short4v lo = *(const short4v*)(lut4 + (byt & 15u) * 4);
        short4v hi = *(const short4v*)(lut4 + (byt >> 4) * 4);
        short8 af;
        af[0] = lo[0]; af[1] = lo[1]; af[2] = lo[2]; af[3] = lo[3];
        af[4] = hi[0]; af[5] = hi[1]; af[6] = hi[2]; af[7] = hi[3];
#pragma unroll
        for (int f = 0; f < 4; ++f)
          acc2[mi][f] = __builtin_amdgcn_mfma_f32_16x16x32_bf16(af, bfv[f], acc2[mi][f], 0, 0, 0);
      }
    }
  }

  // ---- epilogue: s(n) = sum_m relu(dis_m * C[m][n] + b2[n]); pool across waves
#pragma unroll
  for (int f = 0; f < 4; ++f) {
    float b2v = b2[q * 64 + f * 16 + l15];
    float s = 0.f;
#pragma unroll
    for (int mi = 0; mi < 4; ++mi) {
      int mt = wv + mi * 8;
      if (mt < 25) {
        float4 d4 = *(const float4*)(sd + mt * 16 + l4 * 4);
        s += fmaxf(d4.x * acc2[mi][f][0] + b2v, 0.f)
           + fmaxf(d4.y * acc2[mi][f][1] + b2v, 0.f)
           + fmaxf(d4.z * acc2[mi][f][2] + b2v, 0.f)
           + fmaxf(d4.w * acc2[mi][f][3] + b2v, 0.f);
      }
    }
    s += __shfl_xor(s, 16);
    s += __shfl_xor(s, 32);
    if (l4 == 0) pool[wv * 64 + f * 16 + l15] = s;  // pool aliases dead ppL/qqL
  }
  __syncthreads();
  if (t < 64) {
    float sum = 0.f;
#pragma unroll
    for (int w8 = 0; w8 < 8; ++w8) sum += pool[w8 * 64 + t];
    pooled[(size_t)bg * HH + q * 64 + t] = sum;
  }
}

// ---- K5: logits = (pooled/400) @ Wlin + blin. 4 graphs per block
//      (halves Wlin L2 re-reads vs 2/block).
__global__ __launch_bounds__(256) void k_out(
    const float* __restrict__ pooled, const float* __restrict__ Wlin,
    const float* __restrict__ blin, float* __restrict__ out) {
  int bb = blockIdx.x * 4, t = threadIdx.x;
  __shared__ float ps[4][HH];
#pragma unroll
  for (int g = 0; g < 4; ++g)
    ps[g][t] = pooled[(size_t)(bb + g) * HH + t] * (1.f / 400.f);
  __syncthreads();
#pragma unroll
  for (int c = 0; c < 4; ++c) {
    int o = t + c * 256;
    if (o < OUTD) {
      float base = blin[o];
      float a0 = base, a1 = base, a2 = base, a3 = base;
#pragma unroll 8
      for (int h = 0; h < HH; ++h) {
        float wv = Wlin[h * OUTD + o];
        a0 += ps[0][h] * wv;
        a1 += ps[1][h] * wv;
        a2 += ps[2][h] * wv;
        a3 += ps[3][h] * wv;
      }
      out[(size_t)bb * OUTD + o] = a0;
      out[(size_t)(bb + 1) * OUTD + o] = a1;
      out[(size_t)(bb + 2) * OUTD + o] = a2;
      out[(size_t)(bb + 3) * OUTD + o] = a3;
    }
  }
}

extern "C" void kernel_launch(void* const* d_in, const int* in_sizes, int n_in,
                              void* d_out, int out_size, void* d_ws, size_t ws_size,
                              hipStream_t stream) {
  const float* adj   = (const float*)d_in[0];
  const float* times = (const float*)d_in[1];
  const float* W1    = (const float*)d_in[2];
  const float* b1    = (const float*)d_in[3];
  const float* W2    = (const float*)d_in[4];
  const float* b2    = (const float*)d_in[5];
  const float* Wlin  = (const float*)d_in[6];
  const float* blin  = (const float*)d_in[7];
  float* out = (float*)d_out;

  char* ws = (char*)d_ws;
  size_t off = 0;
  auto alloc = [&](size_t bytes) -> void* {
    void* ptr = ws + off;
    off = (off + bytes + 255) & ~(size_t)255;
    return ptr;
  };
  float* dis    = (float*)alloc((size_t)BATCH * NN * 4);
  float* dd     = (float*)alloc((size_t)BATCH * NN * 4);
  float* pp     = (float*)alloc((size_t)BATCH * NN * 4);
  float* qq     = (float*)alloc((size_t)BATCH * NN * 4);
  float* tproj  = (float*)alloc((size_t)BATCH * HH * 4);
  float* pooled = (float*)alloc((size_t)BATCH * HH * 4);
  short* W2s    = (short*)alloc((size_t)128 * 512 * 2);
  unsigned int* bits = (unsigned int*)alloc((size_t)BATCH * NN * BITW * 4);

  k_tw<<<288, 256, 0, stream>>>(times, W1, tproj, W2, W2s);
  k_prep<<<dim3(BATCH, 25), 256, 0, stream>>>(adj, bits, dis, dd);
  k_pq<<<BATCH, 512, 0, stream>>>(bits, dis, dd, pp, qq);
  k_fused<<<dim3(BATCH, 4), 512, 80000, stream>>>(
      bits, dis, pp, qq, W2s, W1, b1, tproj, b2, pooled);
  k_out<<<64, 256, 0, stream>>>(pooled, Wlin, blin, out);
}